// Round 1
// baseline (234.012 us; speedup 1.0000x reference)
//
#include <hip/hip_runtime.h>

typedef short short8 __attribute__((ext_vector_type(8)));
typedef float f32x4 __attribute__((ext_vector_type(4)));

#define NROWS 65536        // B*T = 32*2048
#define NCOMPACT 640       // compacted+padded OUT columns

__device__ __forceinline__ short f2bf(float f) {
  union { float f; unsigned u; } c; c.f = f;
  unsigned r = (c.u + 0x7fffu + ((c.u >> 16) & 1u)) >> 16;
  return (short)r;
}

// Map compacted column n -> original W3/b3 column (or -1 for zero pad).
// Layout: [0,32): logscales[32+j]  [32,64): biases[32+j]  [64,72): logits[k]
//         [72,96): pad  [96,352): mu[k][32+j]  [352,608): logstd[k][32+j]  [608,640): pad
__device__ __forceinline__ int w3col(int n) {
  if (n < 32)  return 32 + n;            // logscales, dims 32..63 (cols 32..63)
  if (n < 64)  return 96 + (n - 32);     // biases, dims 32..63 (cols 96..127)
  if (n < 72)  return 128 + (n - 64);    // logits (cols 128..135)
  if (n < 96)  return -1;
  if (n < 352) { int q = n - 96;  return 168 + (q >> 5) * 64 + (q & 31); } // mu: 136 + k*64 + (32+j)
  if (n < 608) { int q = n - 352; return 680 + (q >> 5) * 64 + (q & 31); } // logstd: 648 + k*64 + (32+j)
  return -1;
}

// x (fp32 [NROWS][64]) -> xc (bf16 [NROWS][32], only masked-in dims)
__global__ __launch_bounds__(256) void prep_x_kernel(const float* __restrict__ x,
                                                     short* __restrict__ xc) {
  int t = blockIdx.x * 256 + threadIdx.x;
  if (t >= NROWS * 4) return;
  int row = t >> 2, seg = t & 3;
  const float* src = x + (size_t)row * 64 + seg * 8;
  short8 v;
#pragma unroll
  for (int i = 0; i < 8; ++i) v[i] = f2bf(src[i]);
  *(short8*)(xc + (size_t)row * 32 + seg * 8) = v;
}

// Build transposed bf16 weights: w1t[512][32], w2t[512][512], w3t[640][512], b3c[640]
__global__ __launch_bounds__(256) void prep_w_kernel(
    const float* __restrict__ W1, const float* __restrict__ W2,
    const float* __restrict__ W3, const float* __restrict__ b3,
    short* __restrict__ w1t, short* __restrict__ w2t,
    short* __restrict__ w3t, float* __restrict__ b3c) {
  const int NW1 = 512 * 32, NW2 = 512 * 512, NW3 = NCOMPACT * 512;
  int t = blockIdx.x * 256 + threadIdx.x;
  if (t < NW1) {
    int n = t >> 5, k = t & 31;
    w1t[t] = f2bf(W1[k * 512 + n]);
  } else if (t < NW1 + NW2) {
    int i = t - NW1; int n = i >> 9, k = i & 511;
    w2t[i] = f2bf(W2[k * 512 + n]);
  } else if (t < NW1 + NW2 + NW3) {
    int i = t - NW1 - NW2; int n = i >> 9, k = i & 511;
    int c = w3col(n);
    w3t[i] = (c >= 0) ? f2bf(W3[(size_t)k * 1160 + c]) : (short)0;
  } else if (t < NW1 + NW2 + NW3 + NCOMPACT) {
    int n = t - NW1 - NW2 - NW3;
    int c = w3col(n);
    b3c[n] = (c >= 0) ? b3[c] : 0.0f;
  }
}

// C[M][N] = act(A[M][K] @ B^T[N][K] + bias[N]); 128x128 tile, 4 waves, 16x16x32 bf16 MFMA.
// LDS tiles XOR-swizzled per 16B chunk (chunk ^= row & (BK/8-1)) so ds_read_b128 is conflict-free.
template <int BK, bool RELU, bool OUT_BF16>
__global__ __launch_bounds__(256) void gemm_kernel(
    const short* __restrict__ A, const short* __restrict__ B,
    const float* __restrict__ bias, void* __restrict__ C, int K, int N) {
  __shared__ short As[128 * BK];
  __shared__ short Bs[128 * BK];
  const int tid = threadIdx.x;
  const int m0 = blockIdx.x * 128, n0 = blockIdx.y * 128;
  const int lane = tid & 63, wid = tid >> 6;
  const int wm = (wid >> 1) * 64, wn = (wid & 1) * 64;
  const int lr = lane & 15, lk = (lane >> 4) * 8;
  constexpr int CPR = BK / 8;      // 16B chunks per LDS row
  constexpr int SWM = CPR - 1;     // swizzle mask
  constexpr int CHUNKS = 128 * CPR;

  f32x4 acc[4][4] = {};

  for (int kt = 0; kt < K; kt += BK) {
#pragma unroll
    for (int c = tid; c < CHUNKS; c += 256) {
      int row = c / CPR, kc = (c % CPR) * 8;
      int sk = kc ^ ((row & SWM) << 3);
      *(short8*)(&As[row * BK + sk]) =
          *(const short8*)(A + (size_t)(m0 + row) * K + kt + kc);
      *(short8*)(&Bs[row * BK + sk]) =
          *(const short8*)(B + (size_t)(n0 + row) * K + kt + kc);
    }
    __syncthreads();
#pragma unroll
    for (int ks = 0; ks < BK; ks += 32) {
      short8 af[4], bf_[4];
#pragma unroll
      for (int mi = 0; mi < 4; ++mi) {
        int row = wm + mi * 16 + lr;
        int k = (ks + lk) ^ ((row & SWM) << 3);
        af[mi] = *(const short8*)(&As[row * BK + k]);
      }
#pragma unroll
      for (int ni = 0; ni < 4; ++ni) {
        int row = wn + ni * 16 + lr;
        int k = (ks + lk) ^ ((row & SWM) << 3);
        bf_[ni] = *(const short8*)(&Bs[row * BK + k]);
      }
#pragma unroll
      for (int mi = 0; mi < 4; ++mi)
#pragma unroll
        for (int ni = 0; ni < 4; ++ni)
          acc[mi][ni] = __builtin_amdgcn_mfma_f32_16x16x32_bf16(
              af[mi], bf_[ni], acc[mi][ni], 0, 0, 0);
    }
    __syncthreads();
  }

#pragma unroll
  for (int ni = 0; ni < 4; ++ni) {
    int col = n0 + wn + ni * 16 + lr;
    float bv = bias[col];
#pragma unroll
    for (int mi = 0; mi < 4; ++mi) {
#pragma unroll
      for (int j = 0; j < 4; ++j) {
        int row = m0 + wm + mi * 16 + (lane >> 4) * 4 + j;
        float v = acc[mi][ni][j] + bv;
        if (RELU) v = fmaxf(v, 0.0f);
        if (OUT_BF16) ((short*)C)[(size_t)row * N + col] = f2bf(v);
        else          ((float*)C)[(size_t)row * N + col] = v;
      }
    }
  }
}

// Mixture-CDF flow transform. 1 thread per (row, active dim j in [0,32)), K=8 components.
__global__ __launch_bounds__(256) void transform_kernel(
    const float* __restrict__ x, const float* __restrict__ params,
    float* __restrict__ out) {
  int t = blockIdx.x * 256 + threadIdx.x;
  int row = t >> 5, j = t & 31;
  if (row >= NROWS) return;
  const float* p = params + (size_t)row * NCOMPACT;

  // softmax weights over 8 logits (unnormalized; divide by ws at the end)
  float lg[8];
#pragma unroll
  for (int k = 0; k < 8; ++k) lg[k] = p[64 + k];
  float m = lg[0];
#pragma unroll
  for (int k = 1; k < 8; ++k) m = fmaxf(m, lg[k]);
  float w[8], ws = 0.0f;
#pragma unroll
  for (int k = 0; k < 8; ++k) { w[k] = expf(lg[k] - m); ws += w[k]; }

  float xd = x[(size_t)row * 64 + 32 + j];
  float zs = 0.0f, ps = 0.0f;
#pragma unroll
  for (int k = 0; k < 8; ++k) {
    float mu   = p[96 + k * 32 + j];
    float lstd = p[352 + k * 32 + j];
    float istd = expf(-lstd);
    float u = (xd - mu) * istd;
    float cdf = 0.5f * (1.0f + erff(u * 0.70710678118654752f));
    zs += w[k] * cdf;
    ps += w[k] * expf(-0.5f * u * u) * istd;
  }
  float z  = zs / ws;
  float pm = (ps / ws) * 0.39894228040143268f;  // 1/sqrt(2*pi)
  float logz = logf(z), log1mz = logf(1.0f - z);
  float ls = p[j], bv = p[32 + j];
  float xs = logz - log1mz;                     // -log(1/z - 1)
  float outv = xs * expf(ls) + bv;
  float ld = logf(pm) - logz - log1mz + ls;

  float* xo  = out;
  float* ldo = out + (size_t)NROWS * 64;
  size_t base = (size_t)row * 64;
  xo[base + j]       = x[base + j];   // passthrough dims 0..31
  xo[base + 32 + j]  = outv;
  ldo[base + j]      = 0.0f;
  ldo[base + 32 + j] = ld;
}

extern "C" void kernel_launch(void* const* d_in, const int* in_sizes, int n_in,
                              void* d_out, int out_size, void* d_ws, size_t ws_size,
                              hipStream_t stream) {
  const float* x  = (const float*)d_in[0];
  const float* W1 = (const float*)d_in[1];
  const float* b1 = (const float*)d_in[2];
  const float* W2 = (const float*)d_in[3];
  const float* b2 = (const float*)d_in[4];
  const float* W3 = (const float*)d_in[5];
  const float* b3 = (const float*)d_in[6];
  char* ws = (char*)d_ws;

  // Workspace layout with lifetime aliasing (total ~226 MB):
  //   params (fp32 [65536][640], 160 MB) overlaps xc+h1 (both dead before GEMM3 writes)
  float* params = (float*)ws;                       // [0, 167772160)
  short* xc  = (short*)ws;                          // [0, 4194304)       bf16 [65536][32]
  short* h1  = (short*)(ws + 4194304);              // [.., 71303168)     bf16 [65536][512]
  short* h2  = (short*)(ws + 167772160);            // 64 MB              bf16 [65536][512]
  short* w1t = (short*)(ws + 234881024);            // 32 KB              bf16 [512][32]
  short* w2t = (short*)(ws + 234913792);            // 512 KB             bf16 [512][512]
  short* w3t = (short*)(ws + 235438080);            // 640 KB             bf16 [640][512]
  float* b3c = (float*)(ws + 236093440);            // 2.5 KB             fp32 [640]
  float* out = (float*)d_out;

  prep_x_kernel<<<(NROWS * 4) / 256, 256, 0, stream>>>(x, xc);
  {
    int total = 512 * 32 + 512 * 512 + NCOMPACT * 512 + NCOMPACT;
    prep_w_kernel<<<(total + 255) / 256, 256, 0, stream>>>(W1, W2, W3, b3, w1t, w2t, w3t, b3c);
  }
  gemm_kernel<32, true,  true ><<<dim3(NROWS / 128, 4), 256, 0, stream>>>(xc, w1t, b1, h1, 32, 512);
  gemm_kernel<64, true,  true ><<<dim3(NROWS / 128, 4), 256, 0, stream>>>(h1, w2t, b2, h2, 512, 512);
  gemm_kernel<64, false, false><<<dim3(NROWS / 128, 5), 256, 0, stream>>>(h2, w3t, b3c, params, 512, NCOMPACT);
  transform_kernel<<<(NROWS * 32) / 256, 256, 0, stream>>>(x, params, out);
}

// Round 2
// 210.509 us; speedup vs baseline: 1.1116x; 1.1116x over previous
//
#include <hip/hip_runtime.h>

typedef short short8 __attribute__((ext_vector_type(8)));
typedef float f32x4 __attribute__((ext_vector_type(4)));

#define NROWS 65536        // B*T = 32*2048
#define NCOMPACT 640       // compacted+padded OUT columns

__device__ __forceinline__ short f2bf(float f) {
  union { float f; unsigned u; } c; c.f = f;
  unsigned r = (c.u + 0x7fffu + ((c.u >> 16) & 1u)) >> 16;
  return (short)r;
}

// Map compacted column n -> original W3/b3 column (or -1 for zero pad).
// Layout: [0,32): logscales[32+j]  [32,64): biases[32+j]  [64,72): logits[k]
//         [72,96): pad  [96,352): mu[k][32+j]  [352,608): logstd[k][32+j]  [608,640): pad
__device__ __forceinline__ int w3col(int n) {
  if (n < 32)  return 32 + n;            // logscales, dims 32..63
  if (n < 64)  return 96 + (n - 32);     // biases, dims 32..63
  if (n < 72)  return 128 + (n - 64);    // logits
  if (n < 96)  return -1;
  if (n < 352) { int q = n - 96;  return 168 + (q >> 5) * 64 + (q & 31); } // mu
  if (n < 608) { int q = n - 352; return 680 + (q >> 5) * 64 + (q & 31); } // logstd
  return -1;
}

// x (fp32 [NROWS][64]) -> xc (bf16 [NROWS][32], only masked-in dims)
__global__ __launch_bounds__(256) void prep_x_kernel(const float* __restrict__ x,
                                                     short* __restrict__ xc) {
  int t = blockIdx.x * 256 + threadIdx.x;
  if (t >= NROWS * 4) return;
  int row = t >> 2, seg = t & 3;
  const float* src = x + (size_t)row * 64 + seg * 8;
  short8 v;
#pragma unroll
  for (int i = 0; i < 8; ++i) v[i] = f2bf(src[i]);
  *(short8*)(xc + (size_t)row * 32 + seg * 8) = v;
}

// Build transposed bf16 weights: w1t[512][32], w2t[512][512], w3t[640][512], b3c[640]
__global__ __launch_bounds__(256) void prep_w_kernel(
    const float* __restrict__ W1, const float* __restrict__ W2,
    const float* __restrict__ W3, const float* __restrict__ b3,
    short* __restrict__ w1t, short* __restrict__ w2t,
    short* __restrict__ w3t, float* __restrict__ b3c) {
  const int NW1 = 512 * 32, NW2 = 512 * 512, NW3 = NCOMPACT * 512;
  int t = blockIdx.x * 256 + threadIdx.x;
  if (t < NW1) {
    int n = t >> 5, k = t & 31;
    w1t[t] = f2bf(W1[k * 512 + n]);
  } else if (t < NW1 + NW2) {
    int i = t - NW1; int n = i >> 9, k = i & 511;
    w2t[i] = f2bf(W2[k * 512 + n]);
  } else if (t < NW1 + NW2 + NW3) {
    int i = t - NW1 - NW2; int n = i >> 9, k = i & 511;
    int c = w3col(n);
    w3t[i] = (c >= 0) ? f2bf(W3[(size_t)k * 1160 + c]) : (short)0;
  } else if (t < NW1 + NW2 + NW3 + NCOMPACT) {
    int n = t - NW1 - NW2 - NW3;
    int c = w3col(n);
    b3c[n] = (c >= 0) ? b3[c] : 0.0f;
  }
}

// C[M][N] = act(A[M][K] @ B^T[N][K] + bias[N]); 128x128 tile, 4 waves, 16x16x32 bf16 MFMA.
// Staging via global_load_lds width=16: LDS kept LINEAR, the XOR swizzle is applied to the
// per-lane GLOBAL source address (rule #21: linear dest + inverse-swz source + swz on read).
// LDS[row][kc] holds A[row][kc ^ swz(row)]; read side XORs again to recover A[row][k].
template <int BK, bool RELU, bool OUT_BF16>
__global__ __launch_bounds__(256) void gemm_kernel(
    const short* __restrict__ A, const short* __restrict__ B,
    const float* __restrict__ bias, void* __restrict__ C, int K, int N) {
  __shared__ short As[128 * BK];
  __shared__ short Bs[128 * BK];
  const int tid = threadIdx.x;
  const int m0 = blockIdx.x * 128, n0 = blockIdx.y * 128;
  const int lane = tid & 63, wid = tid >> 6;
  const int wm = (wid >> 1) * 64, wn = (wid & 1) * 64;
  const int lr = lane & 15, lk = (lane >> 4) * 8;
  constexpr int CPR = BK / 8;      // 16B chunks per LDS row
  constexpr int SWM = CPR - 1;     // swizzle mask (in 16B-chunk units)
  constexpr int NCHUNK = 128 * CPR;

  f32x4 acc[4][4] = {};

  for (int kt = 0; kt < K; kt += BK) {
    // --- stage A,B tiles: HBM -> LDS direct, pre-swizzled source addresses ---
    for (int base = wid * 64; base < NCHUNK; base += 256) {
      int c = base + lane;
      int row = c / CPR;
      int kb = (c % CPR) << 4;                       // byte offset within LDS row
      int skb = kb ^ ((row & SWM) << 4);             // pre-swizzled source byte offset
      const char* ga = (const char*)(A + (size_t)(m0 + row) * K + kt) + skb;
      const char* gb = (const char*)(B + (size_t)(n0 + row) * K + kt) + skb;
      __builtin_amdgcn_global_load_lds(
          (const __attribute__((address_space(1))) void*)ga,
          (__attribute__((address_space(3))) void*)((char*)As + (size_t)base * 16), 16, 0, 0);
      __builtin_amdgcn_global_load_lds(
          (const __attribute__((address_space(1))) void*)gb,
          (__attribute__((address_space(3))) void*)((char*)Bs + (size_t)base * 16), 16, 0, 0);
    }
    __syncthreads();
#pragma unroll
    for (int ks = 0; ks < BK; ks += 32) {
      short8 af[4], bf_[4];
#pragma unroll
      for (int mi = 0; mi < 4; ++mi) {
        int row = wm + mi * 16 + lr;
        int k = (ks + lk) ^ ((row & SWM) << 3);
        af[mi] = *(const short8*)(&As[row * BK + k]);
      }
#pragma unroll
      for (int ni = 0; ni < 4; ++ni) {
        int row = wn + ni * 16 + lr;
        int k = (ks + lk) ^ ((row & SWM) << 3);
        bf_[ni] = *(const short8*)(&Bs[row * BK + k]);
      }
#pragma unroll
      for (int mi = 0; mi < 4; ++mi)
#pragma unroll
        for (int ni = 0; ni < 4; ++ni)
          acc[mi][ni] = __builtin_amdgcn_mfma_f32_16x16x32_bf16(
              af[mi], bf_[ni], acc[mi][ni], 0, 0, 0);
    }
    __syncthreads();
  }

#pragma unroll
  for (int ni = 0; ni < 4; ++ni) {
    int col = n0 + wn + ni * 16 + lr;
    float bv = bias[col];
#pragma unroll
    for (int mi = 0; mi < 4; ++mi) {
#pragma unroll
      for (int j = 0; j < 4; ++j) {
        int row = m0 + wm + mi * 16 + (lane >> 4) * 4 + j;
        float v = acc[mi][ni][j] + bv;
        if (RELU) v = fmaxf(v, 0.0f);
        if (OUT_BF16) ((short*)C)[(size_t)row * N + col] = f2bf(v);
        else          ((float*)C)[(size_t)row * N + col] = v;
      }
    }
  }
}

// Mixture-CDF flow transform. 1 thread per (row, active dim j in [0,32)), K=8 components.
__global__ __launch_bounds__(256) void transform_kernel(
    const float* __restrict__ x, const float* __restrict__ params,
    float* __restrict__ out) {
  int t = blockIdx.x * 256 + threadIdx.x;
  int row = t >> 5, j = t & 31;
  if (row >= NROWS) return;
  const float* p = params + (size_t)row * NCOMPACT;

  float lg[8];
#pragma unroll
  for (int k = 0; k < 8; ++k) lg[k] = p[64 + k];
  float m = lg[0];
#pragma unroll
  for (int k = 1; k < 8; ++k) m = fmaxf(m, lg[k]);
  float w[8], ws = 0.0f;
#pragma unroll
  for (int k = 0; k < 8; ++k) { w[k] = expf(lg[k] - m); ws += w[k]; }

  float xd = x[(size_t)row * 64 + 32 + j];
  float zs = 0.0f, ps = 0.0f;
#pragma unroll
  for (int k = 0; k < 8; ++k) {
    float mu   = p[96 + k * 32 + j];
    float lstd = p[352 + k * 32 + j];
    float istd = expf(-lstd);
    float u = (xd - mu) * istd;
    float cdf = 0.5f * (1.0f + erff(u * 0.70710678118654752f));
    zs += w[k] * cdf;
    ps += w[k] * expf(-0.5f * u * u) * istd;
  }
  float z  = zs / ws;
  float pm = (ps / ws) * 0.39894228040143268f;  // 1/sqrt(2*pi)
  float logz = logf(z), log1mz = logf(1.0f - z);
  float ls = p[j], bv = p[32 + j];
  float xs = logz - log1mz;                     // -log(1/z - 1)
  float outv = xs * expf(ls) + bv;
  float ld = logf(pm) - logz - log1mz + ls;

  float* xo  = out;
  float* ldo = out + (size_t)NROWS * 64;
  size_t base = (size_t)row * 64;
  xo[base + j]       = x[base + j];   // passthrough dims 0..31
  xo[base + 32 + j]  = outv;
  ldo[base + j]      = 0.0f;
  ldo[base + 32 + j] = ld;
}

extern "C" void kernel_launch(void* const* d_in, const int* in_sizes, int n_in,
                              void* d_out, int out_size, void* d_ws, size_t ws_size,
                              hipStream_t stream) {
  const float* x  = (const float*)d_in[0];
  const float* W1 = (const float*)d_in[1];
  const float* b1 = (const float*)d_in[2];
  const float* W2 = (const float*)d_in[3];
  const float* b2 = (const float*)d_in[4];
  const float* W3 = (const float*)d_in[5];
  const float* b3 = (const float*)d_in[6];
  char* ws = (char*)d_ws;

  // Workspace layout with lifetime aliasing (total ~226 MB):
  //   params (fp32 [65536][640], 160 MB) overlaps xc+h1 (both dead before GEMM3 writes)
  float* params = (float*)ws;                       // [0, 167772160)
  short* xc  = (short*)ws;                          // [0, 4194304)       bf16 [65536][32]
  short* h1  = (short*)(ws + 4194304);              // [.., 71303168)     bf16 [65536][512]
  short* h2  = (short*)(ws + 167772160);            // 64 MB              bf16 [65536][512]
  short* w1t = (short*)(ws + 234881024);            // 32 KB              bf16 [512][32]
  short* w2t = (short*)(ws + 234913792);            // 512 KB             bf16 [512][512]
  short* w3t = (short*)(ws + 235438080);            // 640 KB             bf16 [640][512]
  float* b3c = (float*)(ws + 236093440);            // 2.5 KB             fp32 [640]
  float* out = (float*)d_out;

  prep_x_kernel<<<(NROWS * 4) / 256, 256, 0, stream>>>(x, xc);
  {
    int total = 512 * 32 + 512 * 512 + NCOMPACT * 512 + NCOMPACT;
    prep_w_kernel<<<(total + 255) / 256, 256, 0, stream>>>(W1, W2, W3, b3, w1t, w2t, w3t, b3c);
  }
  gemm_kernel<32, true,  true ><<<dim3(NROWS / 128, 4), 256, 0, stream>>>(xc, w1t, b1, h1, 32, 512);
  gemm_kernel<64, true,  true ><<<dim3(NROWS / 128, 4), 256, 0, stream>>>(h1, w2t, b2, h2, 512, 512);
  gemm_kernel<64, false, false><<<dim3(NROWS / 128, 5), 256, 0, stream>>>(h2, w3t, b3c, params, 512, NCOMPACT);
  transform_kernel<<<(NROWS * 32) / 256, 256, 0, stream>>>(x, params, out);
}